// Round 1
// baseline (385.484 us; speedup 1.0000x reference)
//
#include <hip/hip_runtime.h>
#include <math.h>

// Problem constants (from reference setup_inputs)
#define L_SEQ 1024
#define BATCH 64
#define HDIM  1024
#define WPB   4      // waves per block (256 threads)
#define NL    4      // rows processed per online-softmax step

static __device__ __forceinline__ float4 f4_scale(float4 a, float s) {
    return make_float4(a.x * s, a.y * s, a.z * s, a.w * s);
}
static __device__ __forceinline__ float4 f4_fma(float4 acc, float s, float4 b) {
    return make_float4(acc.x + s * b.x, acc.y + s * b.y,
                       acc.z + s * b.z, acc.w + s * b.w);
}

// ---------------------------------------------------------------------------
// Kernel 1: per-(batch, l-chunk) online-softmax partials, NL rows at a time.
// One wave per (b, chunk). Lane j owns h = {4j, 256+4j, 512+4j, 768+4j}
// (float4-strided so each vector load of 64 lanes x 16B = 1KB contiguous).
// Batching NL=4 rows:
//   - 16 independent global float4 loads in flight per step (MLP)
//   - the 6-step wave64 butterfly runs on 4 independent values (latency
//     amortized ~4x: the serial ds-permute chain was the old bottleneck)
//   - the m/lsum/acc rescale chain runs once per 4 rows, not per row.
// ---------------------------------------------------------------------------
__global__ __launch_bounds__(256, 4) void attn_partial_kernel(
    const float* __restrict__ enc, const float* __restrict__ dec,
    float* __restrict__ wsC, float* __restrict__ wsML,
    int split, int chunk)
{
    const int tid  = threadIdx.x;
    const int lane = tid & 63;
    const int wave = tid >> 6;
    const int w    = blockIdx.x * WPB + wave;   // global wave id
    const int b    = w / split;
    const int k    = w - b * split;
    const int l0   = k * chunk;

    // This lane's slice of dec[b,:] (16 floats = 4 float4)
    const float4* decv = (const float4*)(dec + (size_t)b * HDIM);
    float4 d[4];
    #pragma unroll
    for (int q = 0; q < 4; ++q) d[q] = decv[lane + 64 * q];

    float m = -INFINITY;
    float lsum = 0.0f;
    float4 acc[4];
    #pragma unroll
    for (int q = 0; q < 4; ++q) acc[q] = make_float4(0.f, 0.f, 0.f, 0.f);

    // row base pointer, strength-reduced: row stride = BATCH*HDIM floats
    const float* base = enc + ((size_t)l0 * BATCH + b) * HDIM;
    const size_t row_stride = (size_t)BATCH * HDIM;

    for (int l = 0; l < chunk; l += NL) {
        float4 e[NL][4];
        // ---- 16 independent coalesced loads ----
        #pragma unroll
        for (int r = 0; r < NL; ++r) {
            const float4* row = (const float4*)(base + (size_t)r * row_stride);
            #pragma unroll
            for (int q = 0; q < 4; ++q) e[r][q] = row[lane + 64 * q];
        }
        base += (size_t)NL * row_stride;

        // ---- per-lane partial dots (16 elems each) ----
        float s[NL];
        #pragma unroll
        for (int r = 0; r < NL; ++r) {
            float p = 0.f;
            #pragma unroll
            for (int q = 0; q < 4; ++q) {
                p += e[r][q].x * d[q].x + e[r][q].y * d[q].y
                   + e[r][q].z * d[q].z + e[r][q].w * d[q].w;
            }
            s[r] = p;
        }

        // ---- wave64 butterfly on 4 independent values (pipelined) ----
        #pragma unroll
        for (int off = 32; off > 0; off >>= 1) {
            #pragma unroll
            for (int r = 0; r < NL; ++r)
                s[r] += __shfl_xor(s[r], off, 64);
        }

        // ---- online softmax update, once per NL rows ----
        float mn = fmaxf(fmaxf(s[0], s[1]), fmaxf(s[2], s[3]));
        mn = fmaxf(mn, m);
        const float scale = __expf(m - mn);   // exp(-inf - x) = 0 on first iter
        m = mn;
        const float p0 = __expf(s[0] - mn);
        const float p1 = __expf(s[1] - mn);
        const float p2 = __expf(s[2] - mn);
        const float p3 = __expf(s[3] - mn);
        lsum = lsum * scale + (p0 + p1 + p2 + p3);

        #pragma unroll
        for (int q = 0; q < 4; ++q) {
            float4 t = f4_scale(acc[q], scale);
            t = f4_fma(t, p0, e[0][q]);
            t = f4_fma(t, p1, e[1][q]);
            t = f4_fma(t, p2, e[2][q]);
            t = f4_fma(t, p3, e[3][q]);
            acc[q] = t;
        }
    }

    // write partial record
    const size_t r = (size_t)b * split + k;
    float4* C = (float4*)(wsC + r * (size_t)HDIM);
    #pragma unroll
    for (int q = 0; q < 4; ++q) C[lane + 64 * q] = acc[q];
    if (lane == 0) {
        wsML[2 * r]     = m;
        wsML[2 * r + 1] = lsum;
    }
}

// ---------------------------------------------------------------------------
// Kernel 2: combine split partials per batch, write context[b,h].
// Grid = BATCH*4 blocks (one per (b, h-quarter)) x 64 threads, so the tail
// reduce uses all CUs instead of 64. Thread t owns float4 at h-quarter q.
// ---------------------------------------------------------------------------
__global__ __launch_bounds__(64) void attn_reduce_kernel(
    const float* __restrict__ wsC, const float* __restrict__ wsML,
    float* __restrict__ out, int split)
{
    const int b  = blockIdx.x >> 2;
    const int q  = blockIdx.x & 3;
    const int t  = threadIdx.x;        // 0..63
    const int f4 = q * 64 + t;         // float4 index within the row

    float M = -INFINITY;
    for (int k = 0; k < split; ++k)
        M = fmaxf(M, wsML[2 * ((size_t)b * split + k)]);

    float Ltot = 0.0f;
    float4 acc = make_float4(0.f, 0.f, 0.f, 0.f);
    for (int k = 0; k < split; ++k) {
        const size_t r = (size_t)b * split + k;
        const float wgt = __expf(wsML[2 * r] - M);
        Ltot += wsML[2 * r + 1] * wgt;
        const float4 c = ((const float4*)(wsC + r * (size_t)HDIM))[f4];
        acc.x += c.x * wgt;  acc.y += c.y * wgt;
        acc.z += c.z * wgt;  acc.w += c.w * wgt;
    }
    const float inv = 1.0f / Ltot;
    ((float4*)(out + (size_t)b * HDIM))[f4] =
        make_float4(acc.x * inv, acc.y * inv, acc.z * inv, acc.w * inv);
}

extern "C" void kernel_launch(void* const* d_in, const int* in_sizes, int n_in,
                              void* d_out, int out_size, void* d_ws, size_t ws_size,
                              hipStream_t stream) {
    const float* enc = (const float*)d_in[0];   // [L, B, H] fp32
    const float* dec = (const float*)d_in[1];   // [1, B, H] fp32
    float* out = (float*)d_out;                 // [B, H] fp32

    // Largest split whose partials fit in d_ws (ws_size launch-invariant ->
    // identical choice every call -> graph-capture safe). split=64 gives
    // 4096 waves = 4 waves/SIMD across 256 CUs.
    int split = 64;
    while (split > 1) {
        const size_t need = (size_t)BATCH * split * HDIM * sizeof(float)
                          + (size_t)BATCH * split * 2 * sizeof(float);
        if (need <= ws_size) break;
        split >>= 1;
    }
    const int chunk = L_SEQ / split;

    float* wsC  = (float*)d_ws;
    float* wsML = wsC + (size_t)BATCH * split * HDIM;

    const int nblocks = (BATCH * split) / WPB;  // one wave per (b, chunk)
    attn_partial_kernel<<<nblocks, 256, 0, stream>>>(enc, dec, wsC, wsML, split, chunk);
    attn_reduce_kernel<<<BATCH * 4, 64, 0, stream>>>(wsC, wsML, out, split);
}

// Round 2
// 361.691 us; speedup vs baseline: 1.0658x; 1.0658x over previous
//
#include <hip/hip_runtime.h>
#include <math.h>

// Problem constants (from reference setup_inputs)
#define L_SEQ 1024
#define BATCH 64
#define HDIM  1024
#define WPB   4              // waves per block (256 threads)
#define SPLIT 32             // l-chunks per batch (compile-time: static wgt[] indexing)
#define CHUNK (L_SEQ / SPLIT) // 32 rows per wave
#define NL    4              // rows per online-softmax step

static __device__ __forceinline__ float4 f4_scale(float4 a, float s) {
    return make_float4(a.x * s, a.y * s, a.z * s, a.w * s);
}
static __device__ __forceinline__ float4 f4_fma(float4 acc, float s, float4 b) {
    return make_float4(acc.x + s * b.x, acc.y + s * b.y,
                       acc.z + s * b.z, acc.w + s * b.w);
}

// ---------------------------------------------------------------------------
// Kernel 1: per-(batch, l-chunk) online-softmax partials, NL=4 rows/step.
// One wave per (b, chunk); 2048 waves = 8 waves/CU -> only 2 waves/SIMD of
// residency needed, so NO min-waves launch bound (reg cap bought nothing and
// risked spill at ~120 live VGPRs).
// Lane j owns h = {4j, 256+4j, 512+4j, 768+4j}: each float4 load is a
// contiguous 1KB wave transaction. 16 independent loads in flight per step.
// ---------------------------------------------------------------------------
__global__ __launch_bounds__(256) void attn_partial_kernel(
    const float* __restrict__ enc, const float* __restrict__ dec,
    float* __restrict__ wsC, float* __restrict__ wsML)
{
    const int tid  = threadIdx.x;
    const int lane = tid & 63;
    const int wave = tid >> 6;
    const int w    = blockIdx.x * WPB + wave;   // global wave id
    const int b    = w >> 5;                    // w / SPLIT
    const int k    = w & (SPLIT - 1);
    const int l0   = k * CHUNK;

    // This lane's slice of dec[b,:] (16 floats = 4 float4)
    const float4* decv = (const float4*)(dec + (size_t)b * HDIM);
    float4 d[4];
    #pragma unroll
    for (int q = 0; q < 4; ++q) d[q] = decv[lane + 64 * q];

    float m = -INFINITY;
    float lsum = 0.0f;
    float4 acc[4];
    #pragma unroll
    for (int q = 0; q < 4; ++q) acc[q] = make_float4(0.f, 0.f, 0.f, 0.f);

    const float* base = enc + ((size_t)l0 * BATCH + b) * HDIM;
    const size_t row_stride = (size_t)BATCH * HDIM;

    for (int l = 0; l < CHUNK; l += NL) {
        float4 e[NL][4];
        // ---- 16 independent coalesced float4 loads (16 KB/wave in flight) ----
        #pragma unroll
        for (int r = 0; r < NL; ++r) {
            const float4* row = (const float4*)(base + (size_t)r * row_stride);
            #pragma unroll
            for (int q = 0; q < 4; ++q) e[r][q] = row[lane + 64 * q];
        }
        base += (size_t)NL * row_stride;

        // ---- per-lane partial dots ----
        float s[NL];
        #pragma unroll
        for (int r = 0; r < NL; ++r) {
            float p = 0.f;
            #pragma unroll
            for (int q = 0; q < 4; ++q) {
                p += e[r][q].x * d[q].x + e[r][q].y * d[q].y
                   + e[r][q].z * d[q].z + e[r][q].w * d[q].w;
            }
            s[r] = p;
        }

        // ---- wave64 butterfly on 4 independent values (latency amortized) ----
        #pragma unroll
        for (int off = 32; off > 0; off >>= 1) {
            #pragma unroll
            for (int r = 0; r < NL; ++r)
                s[r] += __shfl_xor(s[r], off, 64);
        }

        // ---- online softmax update, once per NL rows ----
        const float mx = fmaxf(fmaxf(s[0], s[1]), fmaxf(s[2], s[3]));
        if (mx > m) {                 // wave-uniform branch (s uniform post-reduce)
            const float scale = __expf(m - mx);   // 0 on first step (m = -inf)
            lsum *= scale;
            #pragma unroll
            for (int q = 0; q < 4; ++q) acc[q] = f4_scale(acc[q], scale);
            m = mx;
        }
        const float p0 = __expf(s[0] - m);
        const float p1 = __expf(s[1] - m);
        const float p2 = __expf(s[2] - m);
        const float p3 = __expf(s[3] - m);
        lsum += p0 + p1 + p2 + p3;

        #pragma unroll
        for (int q = 0; q < 4; ++q) {
            float4 t = acc[q];
            t = f4_fma(t, p0, e[0][q]);
            t = f4_fma(t, p1, e[1][q]);
            t = f4_fma(t, p2, e[2][q]);
            t = f4_fma(t, p3, e[3][q]);
            acc[q] = t;
        }
    }

    // write partial record
    const size_t r = (size_t)b * SPLIT + k;
    float4* C = (float4*)(wsC + r * (size_t)HDIM);
    #pragma unroll
    for (int q = 0; q < 4; ++q) C[lane + 64 * q] = acc[q];
    if (lane == 0)
        ((float2*)wsML)[r] = make_float2(m, lsum);
}

// ---------------------------------------------------------------------------
// Kernel 2: combine SPLIT partials per batch. Grid = BATCH*4 blocks (one per
// (b, h-quarter)) x 64 threads.
// Restructured from a serial (load->exp->fma) chain to:
//   phase 1: all SPLIT (m,l) pairs -> wgt[] in registers (static indexing)
//   phase 2: fully unrolled k-loop of INDEPENDENT float4 loads (streaming).
// ---------------------------------------------------------------------------
__global__ __launch_bounds__(64) void attn_reduce_kernel(
    const float* __restrict__ wsC, const float* __restrict__ wsML,
    float* __restrict__ out)
{
    const int b  = blockIdx.x >> 2;
    const int q  = blockIdx.x & 3;
    const int t  = threadIdx.x;        // 0..63
    const int f4 = q * 64 + t;         // float4 index within the row

    const float2* ML = (const float2*)wsML + (size_t)b * SPLIT;

    // Pass 1: global max (same-address loads broadcast; L2-hot)
    float M = -INFINITY;
    #pragma unroll
    for (int k = 0; k < SPLIT; ++k)
        M = fmaxf(M, ML[k].x);

    // Pass 2: weights in registers, Ltot
    float wgt[SPLIT];
    float Ltot = 0.0f;
    #pragma unroll
    for (int k = 0; k < SPLIT; ++k) {
        const float2 ml = ML[k];
        const float wk = __expf(ml.x - M);
        wgt[k] = wk;
        Ltot += ml.y * wk;
    }

    // Pass 3: streaming weighted sum — SPLIT independent float4 loads
    float4 acc = make_float4(0.f, 0.f, 0.f, 0.f);
    #pragma unroll
    for (int k = 0; k < SPLIT; ++k) {
        const float4 c =
            ((const float4*)(wsC + ((size_t)b * SPLIT + k) * HDIM))[f4];
        acc = f4_fma(acc, wgt[k], c);
    }

    const float inv = 1.0f / Ltot;
    ((float4*)(out + (size_t)b * HDIM))[f4] =
        make_float4(acc.x * inv, acc.y * inv, acc.z * inv, acc.w * inv);
}

extern "C" void kernel_launch(void* const* d_in, const int* in_sizes, int n_in,
                              void* d_out, int out_size, void* d_ws, size_t ws_size,
                              hipStream_t stream) {
    const float* enc = (const float*)d_in[0];   // [L, B, H] fp32
    const float* dec = (const float*)d_in[1];   // [1, B, H] fp32
    float* out = (float*)d_out;                 // [B, H] fp32

    // Partials: BATCH*SPLIT records of HDIM floats + (m,l) pairs = 8.4 MB.
    // Workspace is 1 GiB (poison-fill WRITE_SIZE evidence) — always fits.
    float* wsC  = (float*)d_ws;
    float* wsML = wsC + (size_t)BATCH * SPLIT * HDIM;

    const int nblocks = (BATCH * SPLIT) / WPB;  // 512 blocks, one wave per (b,chunk)
    attn_partial_kernel<<<nblocks, 256, 0, stream>>>(enc, dec, wsC, wsML);
    attn_reduce_kernel<<<BATCH * 4, 64, 0, stream>>>(wsC, wsML, out);
}